// Round 1
// baseline (524.101 us; speedup 1.0000x reference)
//
#include <hip/hip_runtime.h>
#include <hip/hip_bf16.h>
#include <stdint.h>

// y = sum_{k=0}^{3} h_k * S^k X,  X [8192,128] f32, S [8192,8192] f32.
// Strategy: bf16 MFMA (16x16x32), Z kept column-major (Z^T) in ws so both
// A (S rows) and B (Z^T rows) fragments are contiguous 16B/lane loads.
// Pass 1 converts S->bf16 into ws on the fly; passes 2-3 read bf16 S (L3-resident).

typedef __attribute__((ext_vector_type(8))) short     bf16x8;
typedef __attribute__((ext_vector_type(8))) uint16_t  u16x8;
typedef __attribute__((ext_vector_type(4))) float     f32x4;

#define NN 8192
#define NF 128
#define ZSTRIDE (8192 + 64)   // pad Z^T rows to dodge power-of-2 L2 aliasing

__device__ inline uint16_t f2bf(float f) {
    uint32_t u = __builtin_bit_cast(uint32_t, f);
    u += 0x7fffu + ((u >> 16) & 1u);     // round-to-nearest-even
    return (uint16_t)(u >> 16);
}

// ---- pass 0: y = h0*X ; ZT0 = X^T (bf16, col-major) ------------------------
__global__ __launch_bounds__(256) void k_prep(const float* __restrict__ X,
                                              const float* __restrict__ coeff,
                                              float* __restrict__ y,
                                              uint16_t* __restrict__ ZT0) {
    __shared__ float tile[16][NF + 4];
    const int t  = threadIdx.x;
    const int r0 = blockIdx.x * 16;
    const float h0 = coeff[0];
#pragma unroll
    for (int i = 0; i < 2; ++i) {
        int o   = (i * 256 + t) * 4;          // 0..2047
        int row = o >> 7, col = o & 127;
        f32x4 v = *(const f32x4*)(X + (size_t)(r0 + row) * NF + col);
        *(f32x4*)&tile[row][col] = v;
        *(f32x4*)(y + (size_t)(r0 + row) * NF + col) = v * h0;
    }
    __syncthreads();
    const int c = t >> 1, rh = t & 1;
    u16x8 pk;
#pragma unroll
    for (int e = 0; e < 8; ++e) pk[e] = f2bf(tile[rh * 8 + e][c]);
    *(u16x8*)(ZT0 + (size_t)c * ZSTRIDE + r0 + rh * 8) = pk;
}

// ---- GEMM pass: Zk = S * Zk-1 ; y += h_k * Zk ; optionally Zk^T out --------
// block: 32 output rows x 128 cols. 8 waves = 2 r-tiles x 4 k-quarters.
// wave w: rt = w&1 (16-row tile), kq = w>>1 (2048-wide K slice, 64 steps of 32).
template<int PASS, bool SBF16, bool STORE_S16, bool WRITE_ZT>
__global__ __launch_bounds__(512) void k_gemm(const float* __restrict__ Sf,
                                              const uint16_t* __restrict__ S16in,
                                              const uint16_t* __restrict__ ZTin,
                                              uint16_t* __restrict__ S16out,
                                              uint16_t* __restrict__ ZTout,
                                              float* __restrict__ y,
                                              const float* __restrict__ coeff) {
    __shared__ float red[8][16][NF];          // 64 KB: 8 partial D tiles
    const int t    = threadIdx.x;
    const int lane = t & 63;
    const int w    = t >> 6;                  // 0..7
    const int m    = lane & 15;
    const int g    = lane >> 4;               // 0..3
    const int rt   = w & 1;
    const int kq   = w >> 1;                  // 0..3
    const int r0   = blockIdx.x * 32;

    const size_t srow = (size_t)(r0 + rt * 16 + m) * NN;  // S row of this lane
    const int    k0   = kq * 2048 + g * 8;

    f32x4 acc[8];
#pragma unroll
    for (int i = 0; i < 8; ++i) acc[i] = (f32x4){0.f, 0.f, 0.f, 0.f};

    const uint16_t* zbase = ZTin + (size_t)m * ZSTRIDE;

#pragma unroll 4
    for (int kk = 0; kk < 64; ++kk) {
        const int k = k0 + kk * 32;
        bf16x8 a;
        if (SBF16) {
            a = __builtin_bit_cast(bf16x8, *(const u16x8*)(S16in + srow + k));
        } else {
            f32x4 s0 = *(const f32x4*)(Sf + srow + k);
            f32x4 s1 = *(const f32x4*)(Sf + srow + k + 4);
            u16x8 p;
#pragma unroll
            for (int j = 0; j < 4; ++j) { p[j] = f2bf(s0[j]); p[j + 4] = f2bf(s1[j]); }
            if (STORE_S16) *(u16x8*)(S16out + srow + k) = p;
            a = __builtin_bit_cast(bf16x8, p);
        }
#pragma unroll
        for (int ct = 0; ct < 8; ++ct) {
            bf16x8 b = __builtin_bit_cast(bf16x8,
                *(const u16x8*)(zbase + (size_t)(ct * 16) * ZSTRIDE + k));
            acc[ct] = __builtin_amdgcn_mfma_f32_16x16x32_bf16(a, b, acc[ct], 0, 0, 0);
        }
    }

    // D lane l holds C[r0 + rt*16 + 4g+i][ct*16 + m]  (col=lane&15, row=4g+reg)
#pragma unroll
    for (int ct = 0; ct < 8; ++ct)
#pragma unroll
        for (int i = 0; i < 4; ++i)
            red[w][4 * g + i][ct * 16 + m] = acc[ct][i];
    __syncthreads();

    const float hk = coeff[PASS];
    // phase 1: sum 4 K-partials per output, y += hk * sum, stash sum in red[rt]
#pragma unroll
    for (int h = 0; h < 2; ++h) {
        int o = h * 2048 + t * 4;             // 0..4095, 32x128 outputs
        int row32 = o >> 7, col = o & 127;
        int lrt = row32 >> 4, lr = row32 & 15;
        f32x4 sum = *(const f32x4*)&red[lrt][lr][col];
#pragma unroll
        for (int q = 1; q < 4; ++q)
            sum += *(const f32x4*)&red[lrt + 2 * q][lr][col];
        float* yp = y + (size_t)(r0 + row32) * NF + col;
        f32x4 yv = *(const f32x4*)yp;
        *(f32x4*)yp = yv + sum * hk;
        if (WRITE_ZT) *(f32x4*)&red[lrt][lr][col] = sum;   // owner-only write
    }
    if (WRITE_ZT) {
        __syncthreads();
        // phase 2: write Z^T bf16, 8 consecutive rows per thread (16B stores)
        const int c = t >> 2, rq = t & 3;
        u16x8 pk;
#pragma unroll
        for (int e = 0; e < 8; ++e)
            pk[e] = f2bf(red[rq >> 1][(rq & 1) * 8 + e][c]);
        *(u16x8*)(ZTout + (size_t)c * ZSTRIDE + r0 + rq * 8) = pk;
    }
}

extern "C" void kernel_launch(void* const* d_in, const int* in_sizes, int n_in,
                              void* d_out, int out_size, void* d_ws, size_t ws_size,
                              hipStream_t stream) {
    const float* X     = (const float*)d_in[0];
    const float* S     = (const float*)d_in[1];
    const float* coeff = (const float*)d_in[2];
    float* y = (float*)d_out;

    uint8_t* ws = (uint8_t*)d_ws;
    const size_t zb     = ((size_t)NF * ZSTRIDE * sizeof(uint16_t) + 255) & ~(size_t)255;
    uint16_t* ZT0 = (uint16_t*)ws;
    uint16_t* ZT1 = (uint16_t*)(ws + zb);
    uint16_t* S16 = (uint16_t*)(ws + 2 * zb);
    const size_t s16bytes = (size_t)NN * NN * sizeof(uint16_t);
    const bool useS16 = ws_size >= 2 * zb + s16bytes + 1024;

    k_prep<<<dim3(512), dim3(256), 0, stream>>>(X, coeff, y, ZT0);

    if (useS16) {
        k_gemm<1, false, true,  true ><<<dim3(256), dim3(512), 0, stream>>>(S, nullptr, ZT0, S16, ZT1, y, coeff);
        k_gemm<2, true,  false, true ><<<dim3(256), dim3(512), 0, stream>>>(nullptr, S16, ZT1, nullptr, ZT0, y, coeff);
        k_gemm<3, true,  false, false><<<dim3(256), dim3(512), 0, stream>>>(nullptr, S16, ZT0, nullptr, nullptr, y, coeff);
    } else {
        k_gemm<1, false, false, true ><<<dim3(256), dim3(512), 0, stream>>>(S, nullptr, ZT0, nullptr, ZT1, y, coeff);
        k_gemm<2, false, false, true ><<<dim3(256), dim3(512), 0, stream>>>(S, nullptr, ZT1, nullptr, ZT0, y, coeff);
        k_gemm<3, false, false, false><<<dim3(256), dim3(512), 0, stream>>>(S, nullptr, ZT0, nullptr, nullptr, y, coeff);
    }
}

// Round 2
// 243.997 us; speedup vs baseline: 2.1480x; 2.1480x over previous
//
#include <hip/hip_runtime.h>
#include <hip/hip_bf16.h>
#include <stdint.h>

// y = sum_{k=0}^{3} h_k * S^k X.  Pipeline:
//   k_convert: S f32 -> S16 bf16 (ws), leaves S16 hot in L3
//   k_prep:    y = h0*X ; ZT0 = X^T bf16 (col-major, padded stride)
//   per pass:  k_gemm (BM=32,BN=128,BK=64, global_load_lds staged, XOR-swizzled
//              LDS, K split across KS blocks -> f32 partials) + k_combine
//              (sum partials, y += h_k*Z, ZT' = bf16 transpose)

typedef __attribute__((ext_vector_type(8))) short     bf16x8;
typedef __attribute__((ext_vector_type(8))) uint16_t  u16x8;
typedef __attribute__((ext_vector_type(4))) float     f32x4;

#define NN 8192
#define NF 128
#define ZSTRIDE (8192 + 64)   // bf16 elements; 16512 B rows (16B-aligned)

__device__ inline uint16_t f2bf(float f) {
    uint32_t u = __builtin_bit_cast(uint32_t, f);
    u += 0x7fffu + ((u >> 16) & 1u);     // round-to-nearest-even
    return (uint16_t)(u >> 16);
}

__device__ inline void gl2lds16(const uint16_t* g, uint8_t* l) {
    __builtin_amdgcn_global_load_lds(
        (const __attribute__((address_space(1))) uint32_t*)g,
        (__attribute__((address_space(3))) uint32_t*)l,
        16, 0, 0);
}

// ---- S f32 -> bf16 ---------------------------------------------------------
__global__ __launch_bounds__(256) void k_convert(const float* __restrict__ S,
                                                 uint16_t* __restrict__ S16) {
    const size_t n8 = (size_t)NN * NN / 8;
    const size_t stride = (size_t)gridDim.x * 256;
    for (size_t i = (size_t)blockIdx.x * 256 + threadIdx.x; i < n8; i += stride) {
        f32x4 a = *(const f32x4*)(S + i * 8);
        f32x4 b = *(const f32x4*)(S + i * 8 + 4);
        u16x8 p;
#pragma unroll
        for (int j = 0; j < 4; ++j) { p[j] = f2bf(a[j]); p[j + 4] = f2bf(b[j]); }
        *(u16x8*)(S16 + i * 8) = p;
    }
}

// ---- y = h0*X ; ZT0 = X^T bf16 --------------------------------------------
__global__ __launch_bounds__(256) void k_prep(const float* __restrict__ X,
                                              const float* __restrict__ coeff,
                                              float* __restrict__ y,
                                              uint16_t* __restrict__ ZT0) {
    __shared__ float tile[16][NF + 4];
    const int t  = threadIdx.x;
    const int r0 = blockIdx.x * 16;
    const float h0 = coeff[0];
#pragma unroll
    for (int i = 0; i < 2; ++i) {
        int o   = (i * 256 + t) * 4;
        int row = o >> 7, col = o & 127;
        f32x4 v = *(const f32x4*)(X + (size_t)(r0 + row) * NF + col);
        *(f32x4*)&tile[row][col] = v;
        *(f32x4*)(y + (size_t)(r0 + row) * NF + col) = v * h0;
    }
    __syncthreads();
    const int c = t >> 1, rh = t & 1;
    u16x8 pk;
#pragma unroll
    for (int e = 0; e < 8; ++e) pk[e] = f2bf(tile[rh * 8 + e][c]);
    *(u16x8*)(ZT0 + (size_t)c * ZSTRIDE + r0 + rh * 8) = pk;
}

// ---- GEMM pass --------------------------------------------------------------
// grid = 256*KS blocks of 512 thr (8 waves). block: 32 rows x 128 cols,
// K-slice = NN/KS. LDS: dbuf x (A 32x64 + B 128x64) bf16 = 40KB, XOR-swizzled
// in 16B chunks (chunk' = chunk ^ (row&7)) applied on the GLOBAL source and on
// the ds_read address (rule #21: both-sides-or-neither).
template<int KS, bool WRITE_ZT, bool FUSE>
__global__ __launch_bounds__(512, 8) void k_gemm(
    const uint16_t* __restrict__ S16, const uint16_t* __restrict__ ZTin,
    float* __restrict__ P, float* __restrict__ y,
    uint16_t* __restrict__ ZTout, const float* __restrict__ coeff, int pass)
{
    __shared__ __align__(16) uint8_t smem[2][20480];   // [buf][A 4KB | B 16KB]
    const int t = threadIdx.x, lane = t & 63, w = t >> 6;
    const int m = lane & 15, g = lane >> 4;
    const int rt = w & 1, wct = w >> 1;
    const int bx = blockIdx.x;
    const int mt = bx & 255;
    const int ks = bx >> 8;
    const int r0 = mt * 32;
    const int kbase0 = ks * (NN / KS);
    constexpr int NT = (NN / KS) / 64;

    // staging sources (pre-swizzled global addresses)
    const uint16_t* asrc = nullptr;
    if (w < 4) {                                  // A chunks 0..255
        int row = t >> 3, c = t & 7;
        asrc = S16 + (size_t)(r0 + row) * NN + kbase0 + ((c ^ (row & 7)) << 3);
    }
    const uint16_t *bsrc0, *bsrc1;                // B chunks 0..511, 512..1023
    {
        int crow = t >> 3, c = t & 7;
        bsrc0 = ZTin + (size_t)crow * ZSTRIDE + kbase0 + ((c ^ (crow & 7)) << 3);
        int q = t + 512; crow = q >> 3; c = q & 7;
        bsrc1 = ZTin + (size_t)crow * ZSTRIDE + kbase0 + ((c ^ (crow & 7)) << 3);
    }

    auto stage = [&](int buf, int kt) {
        const int ko = kt * 64;                   // elements along K
        uint8_t* base = &smem[buf][0];
        if (w < 4) gl2lds16(asrc + ko, base + (w << 10));
        gl2lds16(bsrc0 + ko, base + 4096 + (w << 10));
        gl2lds16(bsrc1 + ko, base + 4096 + 8192 + (w << 10));
    };

    // ds_read offsets (swizzled); kstep1 = kstep0 ^ 64 (chunk ^ 4)
    const int swz  = ((g ^ (m & 7)) << 4);
    const int aoff = (rt * 16 + m) * 128 + swz;
    const int boff0 = 4096 + (wct * 32 + m) * 128 + swz;
    const int boff1 = boff0 + 16 * 128;

    f32x4 acc0 = {0.f, 0.f, 0.f, 0.f}, acc1 = {0.f, 0.f, 0.f, 0.f};

    stage(0, 0);
    __syncthreads();
    int cur = 0;
#pragma unroll 1
    for (int kt = 0; kt < NT; ++kt) {
        if (kt + 1 < NT) stage(cur ^ 1, kt + 1);
        const uint8_t* bb = &smem[cur][0];
        bf16x8 a0 = __builtin_bit_cast(bf16x8, *(const u16x8*)(bb + aoff));
        bf16x8 a1 = __builtin_bit_cast(bf16x8, *(const u16x8*)(bb + (aoff ^ 64)));
        bf16x8 p0 = __builtin_bit_cast(bf16x8, *(const u16x8*)(bb + boff0));
        bf16x8 p1 = __builtin_bit_cast(bf16x8, *(const u16x8*)(bb + (boff0 ^ 64)));
        bf16x8 q0 = __builtin_bit_cast(bf16x8, *(const u16x8*)(bb + boff1));
        bf16x8 q1 = __builtin_bit_cast(bf16x8, *(const u16x8*)(bb + (boff1 ^ 64)));
        acc0 = __builtin_amdgcn_mfma_f32_16x16x32_bf16(a0, p0, acc0, 0, 0, 0);
        acc1 = __builtin_amdgcn_mfma_f32_16x16x32_bf16(a0, q0, acc1, 0, 0, 0);
        acc0 = __builtin_amdgcn_mfma_f32_16x16x32_bf16(a1, p1, acc0, 0, 0, 0);
        acc1 = __builtin_amdgcn_mfma_f32_16x16x32_bf16(a1, q1, acc1, 0, 0, 0);
        __syncthreads();                          // drains vmcnt too -> next buf ready
        cur ^= 1;
    }

    // D lane: rows rt*16 + 4g+i, cols wct*32 + ct*16 + m
    if (FUSE) {
        float* red = (float*)&smem[0][0];         // 32x128 f32 = 16KB
#pragma unroll
        for (int i = 0; i < 4; ++i) {
            red[(rt * 16 + 4 * g + i) * 128 + wct * 32 + m]      = acc0[i];
            red[(rt * 16 + 4 * g + i) * 128 + wct * 32 + 16 + m] = acc1[i];
        }
        __syncthreads();
        const float hk = coeff[pass];
        {
            int row = t >> 4, col = (t & 15) * 8;
            f32x4 s0 = *(const f32x4*)&red[row * 128 + col];
            f32x4 s1 = *(const f32x4*)&red[row * 128 + col + 4];
            float* yp = y + (size_t)(r0 + row) * NF + col;
            f32x4 y0 = *(const f32x4*)yp, y1 = *(const f32x4*)(yp + 4);
            *(f32x4*)yp       = y0 + hk * s0;
            *(f32x4*)(yp + 4) = y1 + hk * s1;
        }
        if (WRITE_ZT) {
            int c = t >> 2, rq = t & 3;
            u16x8 pk;
#pragma unroll
            for (int e = 0; e < 8; ++e) pk[e] = f2bf(red[(rq * 8 + e) * 128 + c]);
            *(u16x8*)(ZTout + (size_t)c * ZSTRIDE + r0 + rq * 8) = pk;
        }
    } else {
        float* pb = P + ((size_t)ks * NN + r0 + rt * 16 + 4 * g) * NF + wct * 32 + m;
#pragma unroll
        for (int i = 0; i < 4; ++i) {
            pb[i * NF]      = acc0[i];
            pb[i * NF + 16] = acc1[i];
        }
    }
}

// ---- combine: Z = sum_ks P ; y += h*Z ; ZT' = bf16(Z^T) --------------------
template<int KS, bool WRITE_ZT>
__global__ __launch_bounds__(256) void k_combine(const float* __restrict__ P,
                                                 float* __restrict__ y,
                                                 uint16_t* __restrict__ ZTout,
                                                 const float* __restrict__ coeff,
                                                 int pass) {
    __shared__ float tile[16][NF + 4];
    const int t = threadIdx.x, r0 = blockIdx.x * 16;
    const float hk = coeff[pass];
    const int row = t >> 4, col = (t & 15) * 8;
    const size_t off = (size_t)(r0 + row) * NF + col;
    f32x4 s0 = *(const f32x4*)(P + off);
    f32x4 s1 = *(const f32x4*)(P + off + 4);
#pragma unroll
    for (int k = 1; k < KS; ++k) {
        s0 += *(const f32x4*)(P + (size_t)k * NN * NF + off);
        s1 += *(const f32x4*)(P + (size_t)k * NN * NF + off + 4);
    }
    float* yp = y + off;
    f32x4 y0 = *(const f32x4*)yp, y1 = *(const f32x4*)(yp + 4);
    *(f32x4*)yp       = y0 + hk * s0;
    *(f32x4*)(yp + 4) = y1 + hk * s1;
    if (WRITE_ZT) {
        *(f32x4*)&tile[row][col]     = s0;
        *(f32x4*)&tile[row][col + 4] = s1;
        __syncthreads();
        const int c = t >> 1, rh = t & 1;
        u16x8 pk;
#pragma unroll
        for (int e = 0; e < 8; ++e) pk[e] = f2bf(tile[rh * 8 + e][c]);
        *(u16x8*)(ZTout + (size_t)c * ZSTRIDE + r0 + rh * 8) = pk;
    }
}

extern "C" void kernel_launch(void* const* d_in, const int* in_sizes, int n_in,
                              void* d_out, int out_size, void* d_ws, size_t ws_size,
                              hipStream_t stream) {
    const float* X     = (const float*)d_in[0];
    const float* S     = (const float*)d_in[1];
    const float* coeff = (const float*)d_in[2];
    float* y = (float*)d_out;

    uint8_t* ws = (uint8_t*)d_ws;
    const size_t zb     = ((size_t)NF * ZSTRIDE * sizeof(uint16_t) + 255) & ~(size_t)255;
    const size_t s16b   = (size_t)NN * NN * sizeof(uint16_t);
    const size_t base   = 2 * zb + s16b;
    const size_t pslice = (size_t)NN * NF * sizeof(float);
    uint16_t* ZT0 = (uint16_t*)ws;
    uint16_t* ZT1 = (uint16_t*)(ws + zb);
    uint16_t* S16 = (uint16_t*)(ws + 2 * zb);
    float*    P   = (float*)(ws + base);

    const int KS = (ws_size >= base + 4 * pslice) ? 4
                 : (ws_size >= base + 2 * pslice) ? 2 : 1;

    k_convert<<<dim3(2048), dim3(256), 0, stream>>>(S, S16);
    k_prep<<<dim3(512), dim3(256), 0, stream>>>(X, coeff, y, ZT0);

    if (KS == 4) {
        k_gemm<4, false, false><<<dim3(1024), dim3(512), 0, stream>>>(S16, ZT0, P, y, nullptr, coeff, 1);
        k_combine<4, true ><<<dim3(512), dim3(256), 0, stream>>>(P, y, ZT1, coeff, 1);
        k_gemm<4, false, false><<<dim3(1024), dim3(512), 0, stream>>>(S16, ZT1, P, y, nullptr, coeff, 2);
        k_combine<4, true ><<<dim3(512), dim3(256), 0, stream>>>(P, y, ZT0, coeff, 2);
        k_gemm<4, false, false><<<dim3(1024), dim3(512), 0, stream>>>(S16, ZT0, P, y, nullptr, coeff, 3);
        k_combine<4, false><<<dim3(512), dim3(256), 0, stream>>>(P, y, nullptr, coeff, 3);
    } else if (KS == 2) {
        k_gemm<2, false, false><<<dim3(512), dim3(512), 0, stream>>>(S16, ZT0, P, y, nullptr, coeff, 1);
        k_combine<2, true ><<<dim3(512), dim3(256), 0, stream>>>(P, y, ZT1, coeff, 1);
        k_gemm<2, false, false><<<dim3(512), dim3(512), 0, stream>>>(S16, ZT1, P, y, nullptr, coeff, 2);
        k_combine<2, true ><<<dim3(512), dim3(256), 0, stream>>>(P, y, ZT0, coeff, 2);
        k_gemm<2, false, false><<<dim3(512), dim3(512), 0, stream>>>(S16, ZT0, P, y, nullptr, coeff, 3);
        k_combine<2, false><<<dim3(512), dim3(256), 0, stream>>>(P, y, nullptr, coeff, 3);
    } else {
        k_gemm<1, true,  true ><<<dim3(256), dim3(512), 0, stream>>>(S16, ZT0, nullptr, y, ZT1, coeff, 1);
        k_gemm<1, true,  true ><<<dim3(256), dim3(512), 0, stream>>>(S16, ZT1, nullptr, y, ZT0, coeff, 2);
        k_gemm<1, false, true ><<<dim3(256), dim3(512), 0, stream>>>(S16, ZT0, nullptr, y, nullptr, coeff, 3);
    }
}

// Round 3
// 211.144 us; speedup vs baseline: 2.4822x; 1.1556x over previous
//
#include <hip/hip_runtime.h>
#include <hip/hip_bf16.h>
#include <stdint.h>

// y = sum_{k=0}^{3} h_k * S^k X.
//   k_prep:     y = h0*X ; ZT0 = X^T bf16
//   pass 1:     k_gemm_cv: reads S f32, converts in-kernel (writes S16), GEMM -> P
//   pass 2,3:   k_gemm_bf: reads S16 (L3-hot), GEMM -> P
//   after each: k_combine: Z = sum_ks P ; y += h_k Z ; ZT' = bf16(Z^T)
// GEMM: BM=64,BN=128,BK=64, 512 thr (8 waves = 4 rowtiles x 2 colhalves),
// global_load_lds(16B) staging, XOR-swizzled LDS (swizzle on global source +
// on ds_read addr), double-buffered with COUNTED vmcnt + raw s_barrier
// (stage of tile t+1 stays in flight across the barrier — no vmcnt(0) drain).

typedef __attribute__((ext_vector_type(8))) short     bf16x8;
typedef __attribute__((ext_vector_type(8))) uint16_t  u16x8;
typedef __attribute__((ext_vector_type(4))) uint16_t  u16x4;
typedef __attribute__((ext_vector_type(4))) float     f32x4;

#define NN 8192
#define NF 128
#define ZSTRIDE (8192 + 64)

#define WAITV(n) asm volatile("s_waitcnt vmcnt(" #n ")" ::: "memory")
#define WAITL0   asm volatile("s_waitcnt lgkmcnt(0)" ::: "memory")

__device__ inline uint16_t f2bf(float f) {
    uint32_t u = __builtin_bit_cast(uint32_t, f);
    u += 0x7fffu + ((u >> 16) & 1u);
    return (uint16_t)(u >> 16);
}

__device__ inline void gl2lds16(const void* g, uint8_t* l) {
    __builtin_amdgcn_global_load_lds(
        (const __attribute__((address_space(1))) uint32_t*)g,
        (__attribute__((address_space(3))) uint32_t*)l,
        16, 0, 0);
}

__device__ inline bf16x8 ld16(const uint8_t* p) {
    return __builtin_bit_cast(bf16x8, *(const u16x8*)p);
}

// ---- y = h0*X ; ZT0 = X^T bf16 --------------------------------------------
__global__ __launch_bounds__(256) void k_prep(const float* __restrict__ X,
                                              const float* __restrict__ coeff,
                                              float* __restrict__ y,
                                              uint16_t* __restrict__ ZT0) {
    __shared__ float tile[16][NF + 4];
    const int t  = threadIdx.x;
    const int r0 = blockIdx.x * 16;
    const float h0 = coeff[0];
#pragma unroll
    for (int i = 0; i < 2; ++i) {
        int o   = (i * 256 + t) * 4;
        int row = o >> 7, col = o & 127;
        f32x4 v = *(const f32x4*)(X + (size_t)(r0 + row) * NF + col);
        *(f32x4*)&tile[row][col] = v;
        *(f32x4*)(y + (size_t)(r0 + row) * NF + col) = v * h0;
    }
    __syncthreads();
    const int c = t >> 1, rh = t & 1;
    u16x8 pk;
#pragma unroll
    for (int e = 0; e < 8; ++e) pk[e] = f2bf(tile[rh * 8 + e][c]);
    *(u16x8*)(ZT0 + (size_t)c * ZSTRIDE + r0 + rh * 8) = pk;
}

// ---- pass 2/3 GEMM: bf16 S16 ----------------------------------------------
template<int KS>
__global__ __launch_bounds__(512, 4) void k_gemm_bf(
    const uint16_t* __restrict__ S16, const uint16_t* __restrict__ ZTin,
    float* __restrict__ P)
{
    __shared__ __align__(16) uint8_t smem[2][24576];   // A 8KB | B 16KB
    const int t = threadIdx.x, lane = t & 63;
    const int w = t >> 6, m = lane & 15, g = lane >> 4;
    const int rt = w & 3, ch = w >> 2;
    const int mt = blockIdx.x & 127, ks = blockIdx.x >> 7;
    const int r0 = mt * 64;
    const int kb = ks * (NN / KS);
    constexpr int NT = (NN / KS) / 64;

    const int srow = t >> 3, sc = t & 7;
    const int scs  = (sc ^ (srow & 7)) << 3;
    const uint16_t* asrc = S16  + (size_t)(r0 + srow) * NN + kb + scs;
    const uint16_t* bsrc = ZTin + (size_t)srow * ZSTRIDE   + kb + scs;

    const int sw   = m & 7;
    const int aoff = (rt * 16 + m) * 128 + ((g ^ sw) << 4);
    const int bof  = 8192 + (ch * 64 + m) * 128 + ((g ^ sw) << 4);

    f32x4 acc[4] = {};

    {   // prologue stage(0)
        uint8_t* b = smem[0];
        gl2lds16(asrc, b + t * 16);
        gl2lds16(bsrc, b + 8192 + t * 16);
        gl2lds16(bsrc + (size_t)64 * ZSTRIDE, b + 16384 + t * 16);
    }
    int cur = 0;
#pragma unroll 1
    for (int kt = 0; kt < NT; ++kt) {
        if (kt + 1 < NT) {
            const int ko = (kt + 1) * 64;
            uint8_t* b = smem[cur ^ 1];
            gl2lds16(asrc + ko, b + t * 16);
            gl2lds16(bsrc + ko, b + 8192 + t * 16);
            gl2lds16(bsrc + (size_t)64 * ZSTRIDE + ko, b + 16384 + t * 16);
            WAITV(3);                     // own stage(kt) done; (kt+1) in flight
        } else {
            WAITV(0);
        }
        __builtin_amdgcn_s_barrier();
        __builtin_amdgcn_sched_barrier(0);
        const uint8_t* bb = smem[cur];
        bf16x8 a0 = ld16(bb + aoff);
        bf16x8 a1 = ld16(bb + (aoff ^ 64));
#pragma unroll
        for (int ct = 0; ct < 4; ++ct) {
            acc[ct] = __builtin_amdgcn_mfma_f32_16x16x32_bf16(
                a0, ld16(bb + bof + ct * 16 * 128), acc[ct], 0, 0, 0);
            acc[ct] = __builtin_amdgcn_mfma_f32_16x16x32_bf16(
                a1, ld16(bb + ((bof + ct * 16 * 128) ^ 64)), acc[ct], 0, 0, 0);
        }
        WAITL0;                           // my reads of buf landed
        __builtin_amdgcn_sched_barrier(0);
        __builtin_amdgcn_s_barrier();     // everyone done reading buf
        cur ^= 1;
    }

    float* pb = P + ((size_t)ks * NN + r0 + rt * 16 + 4 * g) * NF + ch * 64 + m;
#pragma unroll
    for (int ct = 0; ct < 4; ++ct)
#pragma unroll
        for (int i = 0; i < 4; ++i)
            pb[(size_t)i * NF + ct * 16] = acc[ct][i];
}

// ---- pass 1 GEMM: f32 S staged, converted in-kernel, S16 written ----------
template<int KS>
__global__ __launch_bounds__(512, 4) void k_gemm_cv(
    const float* __restrict__ Sf, const uint16_t* __restrict__ ZTin,
    float* __restrict__ P, uint16_t* __restrict__ S16)
{
    __shared__ __align__(16) uint8_t smem[2][32768];   // A f32 16KB | B 16KB
    const int t = threadIdx.x, lane = t & 63;
    const int w = t >> 6, m = lane & 15, g = lane >> 4;
    const int rt = w & 3, ch = w >> 2;
    const int mt = blockIdx.x & 127, ks = blockIdx.x >> 7;
    const int r0 = mt * 64;
    const int kb = ks * (NN / KS);
    constexpr int NT = (NN / KS) / 64;

    const int arow = t >> 4, ac = t & 15;           // A chunks t, t+512
    const int acg  = ac ^ ((arow & 7) << 1);        // swizzled f32-chunk col
    const float* asrc = Sf + (size_t)(r0 + arow) * NN + kb + (acg << 2);
    const int brow = t >> 3, bc = t & 7;
    const uint16_t* bsrc = ZTin + (size_t)brow * ZSTRIDE + kb
                           + ((bc ^ (brow & 7)) << 3);

    const int sw  = m & 7;
    const int ab  = (rt * 16 + m) * 256 + (((g * 2) ^ (sw << 1)) << 4);
    const int bof = 16384 + (ch * 64 + m) * 128 + ((g ^ sw) << 4);

    uint16_t* s16o = S16 + (size_t)(r0 + arow) * NN + kb + (acg << 2);

    f32x4 acc[4] = {};

    {
        uint8_t* b = smem[0];
        gl2lds16(asrc, b + t * 16);
        gl2lds16(asrc + (size_t)32 * NN, b + 8192 + t * 16);
        gl2lds16(bsrc, b + 16384 + t * 16);
        gl2lds16(bsrc + (size_t)64 * ZSTRIDE, b + 24576 + t * 16);
    }
    int cur = 0;
#pragma unroll 1
    for (int kt = 0; kt < NT; ++kt) {
        if (kt + 1 < NT) {
            const int ko = (kt + 1) * 64;
            uint8_t* b = smem[cur ^ 1];
            gl2lds16(asrc + ko, b + t * 16);
            gl2lds16(asrc + (size_t)32 * NN + ko, b + 8192 + t * 16);
            gl2lds16(bsrc + ko, b + 16384 + t * 16);
            gl2lds16(bsrc + (size_t)64 * ZSTRIDE + ko, b + 24576 + t * 16);
            WAITV(4);
        } else {
            WAITV(0);
        }
        __builtin_amdgcn_s_barrier();
        __builtin_amdgcn_sched_barrier(0);
        const uint8_t* bb = smem[cur];

        bf16x8 a0, a1;
        {
            f32x4 lo = *(const f32x4*)(bb + ab);
            f32x4 hi = *(const f32x4*)(bb + ab + 16);
            u16x8 p;
#pragma unroll
            for (int j = 0; j < 4; ++j) { p[j] = f2bf(lo[j]); p[j + 4] = f2bf(hi[j]); }
            a0 = __builtin_bit_cast(bf16x8, p);
            lo = *(const f32x4*)(bb + (ab ^ 128));
            hi = *(const f32x4*)(bb + (ab ^ 128) + 16);
#pragma unroll
            for (int j = 0; j < 4; ++j) { p[j] = f2bf(lo[j]); p[j + 4] = f2bf(hi[j]); }
            a1 = __builtin_bit_cast(bf16x8, p);
        }
#pragma unroll
        for (int ct = 0; ct < 4; ++ct) {
            acc[ct] = __builtin_amdgcn_mfma_f32_16x16x32_bf16(
                a0, ld16(bb + bof + ct * 16 * 128), acc[ct], 0, 0, 0);
            acc[ct] = __builtin_amdgcn_mfma_f32_16x16x32_bf16(
                a1, ld16(bb + ((bof + ct * 16 * 128) ^ 64)), acc[ct], 0, 0, 0);
        }
        // convert my two staged A chunks -> S16 (reads own LDS chunk, 8B store)
#pragma unroll
        for (int h = 0; h < 2; ++h) {
            f32x4 v = *(const f32x4*)(bb + h * 8192 + t * 16);
            u16x4 s;
#pragma unroll
            for (int j = 0; j < 4; ++j) s[j] = f2bf(v[j]);
            *(u16x4*)(s16o + (size_t)h * 32 * NN + kt * 64) = s;
        }
        WAITL0;
        __builtin_amdgcn_sched_barrier(0);
        __builtin_amdgcn_s_barrier();
        cur ^= 1;
    }

    float* pb = P + ((size_t)ks * NN + r0 + rt * 16 + 4 * g) * NF + ch * 64 + m;
#pragma unroll
    for (int ct = 0; ct < 4; ++ct)
#pragma unroll
        for (int i = 0; i < 4; ++i)
            pb[(size_t)i * NF + ct * 16] = acc[ct][i];
}

// ---- combine: Z = sum_ks P ; y += h*Z ; ZT' = bf16(Z^T) --------------------
template<int KS, bool WRITE_ZT>
__global__ __launch_bounds__(256) void k_combine(const float* __restrict__ P,
                                                 float* __restrict__ y,
                                                 uint16_t* __restrict__ ZTout,
                                                 const float* __restrict__ coeff,
                                                 int pass) {
    __shared__ float tile[16][NF + 4];
    const int t = threadIdx.x, r0 = blockIdx.x * 16;
    const float hk = coeff[pass];
    const int row = t >> 4, col = (t & 15) * 8;
    const size_t off = (size_t)(r0 + row) * NF + col;
    f32x4 s0 = *(const f32x4*)(P + off);
    f32x4 s1 = *(const f32x4*)(P + off + 4);
#pragma unroll
    for (int k = 1; k < KS; ++k) {
        s0 += *(const f32x4*)(P + (size_t)k * NN * NF + off);
        s1 += *(const f32x4*)(P + (size_t)k * NN * NF + off + 4);
    }
    float* yp = y + off;
    f32x4 y0 = *(const f32x4*)yp, y1 = *(const f32x4*)(yp + 4);
    *(f32x4*)yp       = y0 + hk * s0;
    *(f32x4*)(yp + 4) = y1 + hk * s1;
    if (WRITE_ZT) {
        *(f32x4*)&tile[row][col]     = s0;
        *(f32x4*)&tile[row][col + 4] = s1;
        __syncthreads();
        const int c = t >> 1, rh = t & 1;
        u16x8 pk;
#pragma unroll
        for (int e = 0; e < 8; ++e) pk[e] = f2bf(tile[rh * 8 + e][c]);
        *(u16x8*)(ZTout + (size_t)c * ZSTRIDE + r0 + rh * 8) = pk;
    }
}

template<int KS>
static void run(const float* X, const float* S, const float* coeff, float* y,
                uint16_t* ZT0, uint16_t* ZT1, uint16_t* S16, float* P,
                hipStream_t stream) {
    k_prep<<<dim3(512), dim3(256), 0, stream>>>(X, coeff, y, ZT0);
    k_gemm_cv<KS><<<dim3(128 * KS), dim3(512), 0, stream>>>(S, ZT0, P, S16);
    k_combine<KS, true ><<<dim3(512), dim3(256), 0, stream>>>(P, y, ZT1, coeff, 1);
    k_gemm_bf<KS><<<dim3(128 * KS), dim3(512), 0, stream>>>(S16, ZT1, P);
    k_combine<KS, true ><<<dim3(512), dim3(256), 0, stream>>>(P, y, ZT0, coeff, 2);
    k_gemm_bf<KS><<<dim3(128 * KS), dim3(512), 0, stream>>>(S16, ZT0, P);
    k_combine<KS, false><<<dim3(512), dim3(256), 0, stream>>>(P, y, nullptr, coeff, 3);
}

extern "C" void kernel_launch(void* const* d_in, const int* in_sizes, int n_in,
                              void* d_out, int out_size, void* d_ws, size_t ws_size,
                              hipStream_t stream) {
    const float* X     = (const float*)d_in[0];
    const float* S     = (const float*)d_in[1];
    const float* coeff = (const float*)d_in[2];
    float* y = (float*)d_out;

    uint8_t* ws = (uint8_t*)d_ws;
    const size_t zb     = ((size_t)NF * ZSTRIDE * sizeof(uint16_t) + 255) & ~(size_t)255;
    const size_t s16b   = (size_t)NN * NN * sizeof(uint16_t);
    const size_t base   = 2 * zb + s16b;
    const size_t pslice = (size_t)NN * NF * sizeof(float);
    uint16_t* ZT0 = (uint16_t*)ws;
    uint16_t* ZT1 = (uint16_t*)(ws + zb);
    uint16_t* S16 = (uint16_t*)(ws + 2 * zb);
    float*    P   = (float*)(ws + base);

    if (ws_size >= base + 4 * pslice)
        run<4>(X, S, coeff, y, ZT0, ZT1, S16, P, stream);
    else if (ws_size >= base + 2 * pslice)
        run<2>(X, S, coeff, y, ZT0, ZT1, S16, P, stream);
    else
        run<1>(X, S, coeff, y, ZT0, ZT1, S16, P, stream);
}

// Round 4
// 187.047 us; speedup vs baseline: 2.8020x; 1.1288x over previous
//
#include <hip/hip_runtime.h>
#include <hip/hip_bf16.h>
#include <stdint.h>

// y = sum_{k=0}^{3} h_k * S^k X.
//   k_convert: S f32 -> S16 bf16 (linear stream, nontemporal f32 reads)
//   k_prep:    y = h0*X ; ZT0 = X^T bf16
//   3x: k_gemm_bf (BM=64,BN=128,BK=64, global_load_lds(16B), XOR-swizzled LDS,
//       3-buffer / depth-2 prefetch, counted vmcnt, raw barriers) -> P
//       + k_combine (sum KS partials, y += h_k Z, ZT' = bf16(Z^T))

typedef __attribute__((ext_vector_type(8))) short     bf16x8;
typedef __attribute__((ext_vector_type(8))) uint16_t  u16x8;
typedef __attribute__((ext_vector_type(4))) float     f32x4;

#define NN 8192
#define NF 128
#define ZSTRIDE (8192 + 64)

#define WAITV(n) asm volatile("s_waitcnt vmcnt(" #n ")" ::: "memory")
#define WAITL0   asm volatile("s_waitcnt lgkmcnt(0)" ::: "memory")

__device__ inline uint16_t f2bf(float f) {
    uint32_t u = __builtin_bit_cast(uint32_t, f);
    u += 0x7fffu + ((u >> 16) & 1u);
    return (uint16_t)(u >> 16);
}

__device__ inline void gl2lds16(const void* g, uint8_t* l) {
    __builtin_amdgcn_global_load_lds(
        (const __attribute__((address_space(1))) uint32_t*)g,
        (__attribute__((address_space(3))) uint32_t*)l,
        16, 0, 0);
}

__device__ inline bf16x8 ld16(const uint8_t* p) {
    return __builtin_bit_cast(bf16x8, *(const u16x8*)p);
}

// ---- S f32 -> bf16 (linear, nontemporal reads keep S16 in L3) --------------
__global__ __launch_bounds__(256) void k_convert(const float* __restrict__ S,
                                                 uint16_t* __restrict__ S16) {
    const size_t n8 = (size_t)NN * NN / 8;
    const size_t stride = (size_t)gridDim.x * 256;
    for (size_t i = (size_t)blockIdx.x * 256 + threadIdx.x; i < n8; i += stride) {
        f32x4 a = __builtin_nontemporal_load((const f32x4*)(S + i * 8));
        f32x4 b = __builtin_nontemporal_load((const f32x4*)(S + i * 8 + 4));
        u16x8 p;
#pragma unroll
        for (int j = 0; j < 4; ++j) { p[j] = f2bf(a[j]); p[j + 4] = f2bf(b[j]); }
        *(u16x8*)(S16 + i * 8) = p;
    }
}

// ---- y = h0*X ; ZT0 = X^T bf16 --------------------------------------------
__global__ __launch_bounds__(256) void k_prep(const float* __restrict__ X,
                                              const float* __restrict__ coeff,
                                              float* __restrict__ y,
                                              uint16_t* __restrict__ ZT0) {
    __shared__ float tile[16][NF + 4];
    const int t  = threadIdx.x;
    const int r0 = blockIdx.x * 16;
    const float h0 = coeff[0];
#pragma unroll
    for (int i = 0; i < 2; ++i) {
        int o   = (i * 256 + t) * 4;
        int row = o >> 7, col = o & 127;
        f32x4 v = *(const f32x4*)(X + (size_t)(r0 + row) * NF + col);
        *(f32x4*)&tile[row][col] = v;
        *(f32x4*)(y + (size_t)(r0 + row) * NF + col) = v * h0;
    }
    __syncthreads();
    const int c = t >> 1, rh = t & 1;
    u16x8 pk;
#pragma unroll
    for (int e = 0; e < 8; ++e) pk[e] = f2bf(tile[rh * 8 + e][c]);
    *(u16x8*)(ZT0 + (size_t)c * ZSTRIDE + r0 + rh * 8) = pk;
}

// ---- GEMM: P[ks] = S16[rows, kslice] * Z[kslice, :] ------------------------
// 512 thr (8 waves = 4 rowtiles x 2 colhalves), 3-buffer depth-2 prefetch.
template<int KS>
__global__ __launch_bounds__(512, 4) void k_gemm_bf(
    const uint16_t* __restrict__ S16, const uint16_t* __restrict__ ZTin,
    float* __restrict__ P)
{
    __shared__ __align__(16) uint8_t smem[3][24576];   // A 8KB | B 16KB
    const int t = threadIdx.x, lane = t & 63;
    const int w = t >> 6, m = lane & 15, g = lane >> 4;
    const int rt = w & 3, ch = w >> 2;
    const int mt = blockIdx.x & 127, ks = blockIdx.x >> 7;
    const int r0 = mt * 64;
    const int kb = ks * (NN / KS);
    constexpr int NT = (NN / KS) / 64;

    const int srow = t >> 3, sc = t & 7;
    const int scs  = (sc ^ (srow & 7)) << 3;
    const uint16_t* asrc = S16  + (size_t)(r0 + srow) * NN + kb + scs;
    const uint16_t* bsrc = ZTin + (size_t)srow * ZSTRIDE   + kb + scs;

    const int sw   = m & 7;
    const int aoff = (rt * 16 + m) * 128 + ((g ^ sw) << 4);
    const int bof  = 8192 + (ch * 64 + m) * 128 + ((g ^ sw) << 4);

    f32x4 acc[4] = {};

    auto stage = [&](int buf, int kt) {
        const int ko = kt * 64;
        uint8_t* b = smem[buf];
        gl2lds16(asrc + ko, b + t * 16);
        gl2lds16(bsrc + ko, b + 8192 + t * 16);
        gl2lds16(bsrc + (size_t)64 * ZSTRIDE + ko, b + 16384 + t * 16);
    };

    stage(0, 0);
    stage(1, 1);
    int cur = 0;
#pragma unroll 1
    for (int kt = 0; kt < NT; ++kt) {
        if (kt + 2 < NT) {
            int nxt = cur + 2; if (nxt >= 3) nxt -= 3;
            stage(nxt, kt + 2);
            WAITV(6);                 // stage(kt) done; (kt+1),(kt+2) in flight
        } else if (kt + 2 == NT) {
            WAITV(3);                 // stage(kt) done; (kt+1) in flight
        } else {
            WAITV(0);                 // last tile
        }
        __builtin_amdgcn_s_barrier();
        __builtin_amdgcn_sched_barrier(0);
        const uint8_t* bb = smem[cur];
        bf16x8 a0 = ld16(bb + aoff);
        bf16x8 a1 = ld16(bb + (aoff ^ 64));
#pragma unroll
        for (int ct = 0; ct < 4; ++ct) {
            acc[ct] = __builtin_amdgcn_mfma_f32_16x16x32_bf16(
                a0, ld16(bb + bof + ct * 16 * 128), acc[ct], 0, 0, 0);
            acc[ct] = __builtin_amdgcn_mfma_f32_16x16x32_bf16(
                a1, ld16(bb + ((bof + ct * 16 * 128) ^ 64)), acc[ct], 0, 0, 0);
        }
        WAITL0;                       // my reads of buf landed
        __builtin_amdgcn_sched_barrier(0);
        __builtin_amdgcn_s_barrier(); // everyone done reading buf
        cur = (cur + 1 == 3) ? 0 : cur + 1;
    }

    float* pb = P + ((size_t)ks * NN + r0 + rt * 16 + 4 * g) * NF + ch * 64 + m;
#pragma unroll
    for (int ct = 0; ct < 4; ++ct)
#pragma unroll
        for (int i = 0; i < 4; ++i)
            pb[(size_t)i * NF + ct * 16] = acc[ct][i];
}

// ---- combine: Z = sum_ks P ; y += h*Z ; ZT' = bf16(Z^T) --------------------
template<int KS, bool WRITE_ZT>
__global__ __launch_bounds__(256) void k_combine(const float* __restrict__ P,
                                                 float* __restrict__ y,
                                                 uint16_t* __restrict__ ZTout,
                                                 const float* __restrict__ coeff,
                                                 int pass) {
    __shared__ float tile[16][NF + 4];
    const int t = threadIdx.x, r0 = blockIdx.x * 16;
    const float hk = coeff[pass];
    const int row = t >> 4, col = (t & 15) * 8;
    const size_t off = (size_t)(r0 + row) * NF + col;
    f32x4 s0 = *(const f32x4*)(P + off);
    f32x4 s1 = *(const f32x4*)(P + off + 4);
#pragma unroll
    for (int k = 1; k < KS; ++k) {
        s0 += *(const f32x4*)(P + (size_t)k * NN * NF + off);
        s1 += *(const f32x4*)(P + (size_t)k * NN * NF + off + 4);
    }
    float* yp = y + off;
    f32x4 y0 = *(const f32x4*)yp, y1 = *(const f32x4*)(yp + 4);
    *(f32x4*)yp       = y0 + hk * s0;
    *(f32x4*)(yp + 4) = y1 + hk * s1;
    if (WRITE_ZT) {
        *(f32x4*)&tile[row][col]     = s0;
        *(f32x4*)&tile[row][col + 4] = s1;
        __syncthreads();
        const int c = t >> 1, rh = t & 1;
        u16x8 pk;
#pragma unroll
        for (int e = 0; e < 8; ++e) pk[e] = f2bf(tile[rh * 8 + e][c]);
        *(u16x8*)(ZTout + (size_t)c * ZSTRIDE + r0 + rh * 8) = pk;
    }
}

template<int KS>
static void run(const float* X, const float* S, const float* coeff, float* y,
                uint16_t* ZT0, uint16_t* ZT1, uint16_t* S16, float* P,
                hipStream_t stream) {
    k_prep<<<dim3(512), dim3(256), 0, stream>>>(X, coeff, y, ZT0);
    k_convert<<<dim3(2048), dim3(256), 0, stream>>>(S, S16);
    k_gemm_bf<KS><<<dim3(128 * KS), dim3(512), 0, stream>>>(S16, ZT0, P);
    k_combine<KS, true ><<<dim3(512), dim3(256), 0, stream>>>(P, y, ZT1, coeff, 1);
    k_gemm_bf<KS><<<dim3(128 * KS), dim3(512), 0, stream>>>(S16, ZT1, P);
    k_combine<KS, true ><<<dim3(512), dim3(256), 0, stream>>>(P, y, ZT0, coeff, 2);
    k_gemm_bf<KS><<<dim3(128 * KS), dim3(512), 0, stream>>>(S16, ZT0, P);
    k_combine<KS, false><<<dim3(512), dim3(256), 0, stream>>>(P, y, nullptr, coeff, 3);
}

extern "C" void kernel_launch(void* const* d_in, const int* in_sizes, int n_in,
                              void* d_out, int out_size, void* d_ws, size_t ws_size,
                              hipStream_t stream) {
    const float* X     = (const float*)d_in[0];
    const float* S     = (const float*)d_in[1];
    const float* coeff = (const float*)d_in[2];
    float* y = (float*)d_out;

    uint8_t* ws = (uint8_t*)d_ws;
    const size_t zb     = ((size_t)NF * ZSTRIDE * sizeof(uint16_t) + 255) & ~(size_t)255;
    const size_t s16b   = (size_t)NN * NN * sizeof(uint16_t);
    const size_t base   = 2 * zb + s16b;
    const size_t pslice = (size_t)NN * NF * sizeof(float);
    uint16_t* ZT0 = (uint16_t*)ws;
    uint16_t* ZT1 = (uint16_t*)(ws + zb);
    uint16_t* S16 = (uint16_t*)(ws + 2 * zb);
    float*    P   = (float*)(ws + base);

    if (ws_size >= base + 4 * pslice)
        run<4>(X, S, coeff, y, ZT0, ZT1, S16, P, stream);
    else if (ws_size >= base + 2 * pslice)
        run<2>(X, S, coeff, y, ZT0, ZT1, S16, P, stream);
    else
        run<1>(X, S, coeff, y, ZT0, ZT1, S16, P, stream);
}